// Round 20
// baseline (382.347 us; speedup 1.0000x reference)
//
#include <hip/hip_runtime.h>
#include <hip/hip_bf16.h>

#define N_LIG 100000
#define N_TGT 20000
#define NEDGE 1000000
#define H 128
#define NXCD 8
#define RL 12500   // ligand ids per partition (8*12500 = 100000)
#define RT 2500    // target ids per partition (8*2500 = 20000)
#define CAP 131072 // per-bucket capacity (mean 125000, sigma ~331)
#define NSLICE 16  // sub-slices per bucket for count/fill
#define NSLB (NSLICE * NXCD)  // 128 blocks per side
#define BBLK 512             // bin_edges grid
#define BCHUNK ((NEDGE + BBLK - 1) / BBLK)  // 1954 edges per block

typedef __attribute__((ext_vector_type(8))) short short8v;
typedef __attribute__((ext_vector_type(4))) float f32x4;
typedef __attribute__((ext_vector_type(4))) unsigned int uint4v;

// ---- bf16 helpers (manual RTN-even, bit ops only) ----
__device__ __forceinline__ unsigned short f2bs(float f) {
    unsigned int u = __float_as_uint(f);
    u += 0x7fff + ((u >> 16) & 1);
    return (unsigned short)(u >> 16);
}
__device__ __forceinline__ float bs2f(unsigned int s) {
    return __uint_as_float(s << 16);
}

// ---------------- weight transpose+convert: W[K][128] f32 -> Wt[128][K] bf16 ----------------
__global__ void transpose_w(const float* __restrict__ W, unsigned short* __restrict__ Wt, int K) {
    int idx = blockIdx.x * blockDim.x + threadIdx.x;
    if (idx >= K * 128) return;
    int k = idx >> 7, c = idx & 127;
    Wt[(size_t)c * K + k] = f2bs(W[idx]);
}

// six 128x128 transposes in one launch
struct P6 { const float* w[6]; unsigned short* o[6]; };
__global__ void transpose6(P6 p) {
    int idx = blockIdx.x * blockDim.x + threadIdx.x;  // 6*16384
    int which = idx >> 14;
    int rem = idx & 16383;
    int k = rem >> 7, c = rem & 127;
    p.o[which][(size_t)c * 128 + k] = f2bs(p.w[which][rem]);
}

// ---------------- ligand embed: K=4, bf16 out ----------------
__global__ void lin4_bf16(const float* __restrict__ X, const float* __restrict__ W,
                          const float* __restrict__ b, unsigned short* __restrict__ Y, int N) {
    int idx = blockIdx.x * blockDim.x + threadIdx.x;  // N*16, 8 cols each
    if (idx >= N * 16) return;
    int r = idx >> 4;
    int c = (idx & 15) * 8;
    float x0 = X[r * 4 + 0], x1 = X[r * 4 + 1], x2 = X[r * 4 + 2], x3 = X[r * 4 + 3];
    unsigned int o[4];
#pragma unroll
    for (int p = 0; p < 4; ++p) {
        float v0 = b[c + 2 * p] + x0 * W[c + 2 * p] + x1 * W[H + c + 2 * p] +
                   x2 * W[2 * H + c + 2 * p] + x3 * W[3 * H + c + 2 * p];
        float v1 = b[c + 2 * p + 1] + x0 * W[c + 2 * p + 1] + x1 * W[H + c + 2 * p + 1] +
                   x2 * W[2 * H + c + 2 * p + 1] + x3 * W[3 * H + c + 2 * p + 1];
        o[p] = (unsigned int)f2bs(v0) | ((unsigned int)f2bs(v1) << 16);
    }
    uint4 u = make_uint4(o[0], o[1], o[2], o[3]);
    *(uint4*)&Y[(size_t)r * H + c] = u;
}

// ---------------- MFMA GEMM: Y_bf16[N][128] = act(X_bf16[N][128] @ W + bias) ----------
__launch_bounds__(512)
__global__ void gemm_bf16(const unsigned short* __restrict__ X,
                          const unsigned short* __restrict__ Wt,
                          const float* __restrict__ bias,
                          unsigned short* __restrict__ Y,
                          int N, int do_relu) {
    __shared__ unsigned short Ws[128 * 128];  // 32 KB, swizzled; reused by epilogue
    const int t = threadIdx.x;
    const int wv = t >> 6;
    const int lane = t & 63;
    const int lr = lane & 15;
    const int kb = lane >> 4;
    const int row0 = blockIdx.x * 128;
    const int wrow = wv * 16;

    f32x4 acc[8];
#pragma unroll
    for (int i = 0; i < 8; ++i) acc[i] = (f32x4){0.f, 0.f, 0.f, 0.f};

    int arow = row0 + wrow + lr;
    if (arow >= N) arow = N - 1;
    const unsigned short* xrow = X + (size_t)arow * 128;

#pragma unroll
    for (int i = 0; i < 4; ++i) {
        int li = t + i * 512;
        int r = li >> 4;
        int cb = (li & 15) << 4;
        int4 v = *(const int4*)(Wt + (size_t)r * 128 + (cb >> 1));
        *(int4*)((char*)Ws + r * 256 + (cb ^ ((r & 7) << 4))) = v;
    }
    short8v a[4];
#pragma unroll
    for (int ks = 0; ks < 4; ++ks)
        a[ks] = *(const short8v*)(xrow + ks * 32 + kb * 8);
    __syncthreads();
#pragma unroll
    for (int ks = 0; ks < 4; ++ks) {
        int ofs = ks * 64 + kb * 16;
#pragma unroll
        for (int ct = 0; ct < 8; ++ct) {
            int c = ct * 16 + lr;
            short8v b = *(const short8v*)((const char*)Ws + c * 256 + (ofs ^ ((c & 7) << 4)));
            acc[ct] = __builtin_amdgcn_mfma_f32_16x16x32_bf16(a[ks], b, acc[ct], 0, 0, 0);
        }
    }
    __syncthreads();
#pragma unroll
    for (int ct = 0; ct < 8; ++ct) {
        int col = ct * 16 + lr;
        float bv = bias ? bias[col] : 0.f;
#pragma unroll
        for (int r = 0; r < 4; ++r) {
            float v = acc[ct][r] + bv;
            if (do_relu) v = fmaxf(v, 0.f);
            Ws[(wrow + kb * 4 + r) * 128 + col] = f2bs(v);
        }
    }
    __syncthreads();
#pragma unroll
    for (int i = 0; i < 4; ++i) {
        int li = t + i * 512;
        int r = li >> 4;
        int c8 = (li & 15) << 3;
        int grow = row0 + r;
        if (grow < N)
            *(uint4*)&Y[(size_t)grow * H + c8] = *(const uint4*)&Ws[r * 128 + c8];
    }
}

// ---------------- embed GEMM, K=1280 split-2 in one launch ----------------
__launch_bounds__(512)
__global__ void gemm_embed_split(const float* __restrict__ Xf32,
                                 const unsigned short* __restrict__ Wt,
                                 unsigned short* __restrict__ P0,
                                 unsigned short* __restrict__ P1, int N) {
    __shared__ unsigned short Ws[128 * 128];
    const int t = threadIdx.x;
    const int rb = blockIdx.x >> 1;
    const int sp = blockIdx.x & 1;
    const int K = 1280;
    const int kc0 = sp * 5, kcEnd = kc0 + 5;
    unsigned short* Y = sp ? P1 : P0;
    const int wv = t >> 6;
    const int lane = t & 63;
    const int lr = lane & 15;
    const int kb = lane >> 4;
    const int row0 = rb * 128;
    const int wrow = wv * 16;

    f32x4 acc[8];
#pragma unroll
    for (int i = 0; i < 8; ++i) acc[i] = (f32x4){0.f, 0.f, 0.f, 0.f};

    int arow = row0 + wrow + lr;
    if (arow >= N) arow = N - 1;
    const float* xrowf = Xf32 + (size_t)arow * K;

    for (int kc = kc0; kc < kcEnd; ++kc) {
        if (kc != kc0) __syncthreads();
#pragma unroll
        for (int i = 0; i < 4; ++i) {
            int li = t + i * 512;
            int r = li >> 4;
            int cb = (li & 15) << 4;
            int4 v = *(const int4*)(Wt + (size_t)r * K + (kc << 7) + (cb >> 1));
            *(int4*)((char*)Ws + r * 256 + (cb ^ ((r & 7) << 4))) = v;
        }
        short8v a[4];
#pragma unroll
        for (int ks = 0; ks < 4; ++ks) {
            const float* p = xrowf + (kc << 7) + ks * 32 + kb * 8;
            float4 f0 = *(const float4*)p;
            float4 f1 = *(const float4*)(p + 4);
            short8v av;
            av[0] = (short)f2bs(f0.x); av[1] = (short)f2bs(f0.y);
            av[2] = (short)f2bs(f0.z); av[3] = (short)f2bs(f0.w);
            av[4] = (short)f2bs(f1.x); av[5] = (short)f2bs(f1.y);
            av[6] = (short)f2bs(f1.z); av[7] = (short)f2bs(f1.w);
            a[ks] = av;
        }
        __syncthreads();
#pragma unroll
        for (int ks = 0; ks < 4; ++ks) {
            int ofs = ks * 64 + kb * 16;
#pragma unroll
            for (int ct = 0; ct < 8; ++ct) {
                int c = ct * 16 + lr;
                short8v b = *(const short8v*)((const char*)Ws + c * 256 + (ofs ^ ((c & 7) << 4)));
                acc[ct] = __builtin_amdgcn_mfma_f32_16x16x32_bf16(a[ks], b, acc[ct], 0, 0, 0);
            }
        }
    }
    __syncthreads();
#pragma unroll
    for (int ct = 0; ct < 8; ++ct) {
        int col = ct * 16 + lr;
#pragma unroll
        for (int r = 0; r < 4; ++r)
            Ws[(wrow + kb * 4 + r) * 128 + col] = f2bs(acc[ct][r]);
    }
    __syncthreads();
#pragma unroll
    for (int i = 0; i < 4; ++i) {
        int li = t + i * 512;
        int r = li >> 4;
        int c8 = (li & 15) << 3;
        int grow = row0 + r;
        if (grow < N)
            *(uint4*)&Y[(size_t)grow * H + c8] = *(const uint4*)&Ws[r * 128 + c8];
    }
}

// T0 = bf16(P0 + P1 + bias)
__global__ void reduce_embed(const unsigned int* __restrict__ P0, const unsigned int* __restrict__ P1,
                             const float* __restrict__ bias, unsigned int* __restrict__ T0, int n) {
    int i = blockIdx.x * blockDim.x + threadIdx.x;
    if (i >= n) return;
    int c2 = i & 63;
    unsigned int a = P0[i], b = P1[i];
    float f0 = bs2f(a & 0xffff) + bs2f(b & 0xffff) + bias[2 * c2];
    float f1 = bs2f(a >> 16) + bs2f(b >> 16) + bias[2 * c2 + 1];
    T0[i] = (unsigned int)f2bs(f0) | ((unsigned int)f2bs(f1) << 16);
}

// ---------------- FUSED: A16[node] = (relu(mean(G[nbr])+bias)) @ WtA  ----------------
__launch_bounds__(512)
__global__ void gather_gemm_A(const unsigned short* __restrict__ G,
                              const int* __restrict__ rowptr, const int* __restrict__ nbr,
                              const float* __restrict__ bias,
                              const unsigned short* __restrict__ WtA,
                              unsigned short* __restrict__ A16, int N) {
    __shared__ unsigned short Hs[128 * 128];  // 32 KB node features (swizzled)
    __shared__ unsigned short Ws[128 * 128];  // 32 KB weights (swizzled)
    const int t = threadIdx.x;
    const int row0 = blockIdx.x * 128;
#pragma unroll
    for (int i = 0; i < 4; ++i) {
        int li = t + i * 512;
        int r = li >> 4;
        int cb = (li & 15) << 4;
        int4 v = *(const int4*)(WtA + (size_t)r * 128 + (cb >> 1));
        *(int4*)((char*)Ws + r * 256 + (cb ^ ((r & 7) << 4))) = v;
    }
    const int l16 = t & 15;
    const int g = t >> 4;  // 0..31
    const uint4v* f4 = (const uint4v*)G;
#pragma unroll
    for (int pass = 0; pass < 4; ++pass) {
        int r = pass * 32 + g;
        int node = row0 + r;
        uint4v o = (uint4v){0u, 0u, 0u, 0u};
        if (node < N) {
            int beg = rowptr[node], end = rowptr[node + 1];
            float acc[8] = {0.f, 0.f, 0.f, 0.f, 0.f, 0.f, 0.f, 0.f};
            int j = beg;
            for (; j + 8 <= end; j += 8) {
                uint4v v[8];
#pragma unroll
                for (int q = 0; q < 8; ++q)
                    v[q] = f4[(size_t)(((unsigned int)nbr[(j + q) * 2]) >> 17) * 16 + l16];
#pragma unroll
                for (int q = 0; q < 8; ++q) {
#pragma unroll
                    for (int w = 0; w < 4; ++w) {
                        acc[2 * w] += bs2f(v[q][w] & 0xffff);
                        acc[2 * w + 1] += bs2f(v[q][w] >> 16);
                    }
                }
            }
            for (; j < end; ++j) {
                unsigned int n0 = ((unsigned int)nbr[j * 2]) >> 17;
                uint4v v0 = f4[(size_t)n0 * 16 + l16];
#pragma unroll
                for (int q = 0; q < 4; ++q) {
                    acc[2 * q] += bs2f(v0[q] & 0xffff);
                    acc[2 * q + 1] += bs2f(v0[q] >> 16);
                }
            }
            float inv = 1.f / (float)max(end - beg, 1);
#pragma unroll
            for (int q = 0; q < 4; ++q) {
                float m0 = fmaxf(acc[2 * q] * inv + bias[l16 * 8 + 2 * q], 0.f);
                float m1 = fmaxf(acc[2 * q + 1] * inv + bias[l16 * 8 + 2 * q + 1], 0.f);
                o[q] = (unsigned int)f2bs(m0) | ((unsigned int)f2bs(m1) << 16);
            }
        }
        *(uint4v*)((char*)Hs + r * 256 + ((l16 * 16) ^ ((r & 7) << 4))) = o;
    }
    __syncthreads();
    const int wv = t >> 6;
    const int lane = t & 63;
    const int lr = lane & 15;
    const int kb = lane >> 4;
    const int wrow = wv * 16;
    f32x4 acc[8];
#pragma unroll
    for (int i = 0; i < 8; ++i) acc[i] = (f32x4){0.f, 0.f, 0.f, 0.f};
    const int ar = wrow + lr;
#pragma unroll
    for (int ks = 0; ks < 4; ++ks) {
        int ofs = ks * 64 + kb * 16;
        short8v a = *(const short8v*)((const char*)Hs + ar * 256 + (ofs ^ ((ar & 7) << 4)));
#pragma unroll
        for (int ct = 0; ct < 8; ++ct) {
            int c = ct * 16 + lr;
            short8v b = *(const short8v*)((const char*)Ws + c * 256 + (ofs ^ ((c & 7) << 4)));
            acc[ct] = __builtin_amdgcn_mfma_f32_16x16x32_bf16(a, b, acc[ct], 0, 0, 0);
        }
    }
#pragma unroll
    for (int ct = 0; ct < 8; ++ct) {
        int col = ct * 16 + lr;
#pragma unroll
        for (int r = 0; r < 4; ++r)
            Hs[(wrow + kb * 4 + r) * 128 + col] = f2bs(acc[ct][r]);
    }
#pragma unroll
    for (int i = 0; i < 4; ++i) {
        int li = lane + i * 64;
        int r = li >> 4;
        int c8 = (li & 15) << 3;
        int grow = row0 + wrow + r;
        if (grow < N)
            *(uint4*)&A16[(size_t)grow * H + c8] = *(const uint4*)&Hs[(wrow + r) * 128 + c8];
    }
}

// ---------------- CSR build phase 1: bin edges into 8 XCD buckets (single global read) -----
// lig entry: uint64 (e<<32)|(d<<17)|s ; tgt entry: uint32 (d<<17)|s; e = chunk_beg + lds_idx
__global__ void zero_gcur(int* __restrict__ g) {
    if (threadIdx.x < 16) g[threadIdx.x] = 0;
}

__launch_bounds__(256)
__global__ void bin_edges(const int* __restrict__ es, const int* __restrict__ ed,
                          unsigned long long* __restrict__ bkt_l, unsigned int* __restrict__ bkt_t,
                          int* __restrict__ gcur, int E) {
    __shared__ unsigned int slow[BCHUNK];  // (d<<17)|s per edge, 7.8 KB
    __shared__ int h[16];
    __shared__ int base_s[16];
    int t = threadIdx.x;
    int lane = t & 63;
    if (t < 16) h[t] = 0;
    __syncthreads();
    int beg = blockIdx.x * BCHUNK;
    int end = min(beg + BCHUNK, E);
    int n = end - beg;
    // single global read: stage low into LDS, count via wave-aggregation
    for (int li = t; li < n; li += 256) {
        int s = es[beg + li], d = ed[beg + li];
        slow[li] = ((unsigned int)d << 17) | (unsigned int)s;
        int bl = s / RL, bt = d / RT;
#pragma unroll
        for (int b = 0; b < 8; ++b) {
            unsigned long long m = __ballot(bl == b);
            if (lane == 0 && m) atomicAdd(&h[b], __popcll(m));
            m = __ballot(bt == b);
            if (lane == 0 && m) atomicAdd(&h[8 + b], __popcll(m));
        }
    }
    __syncthreads();
    if (t < 16) {
        base_s[t] = atomicAdd(&gcur[t], h[t]);
        h[t] = 0;
    }
    __syncthreads();
    // write pass from LDS (wave-aggregated rank -> contiguous runs)
    for (int li0 = 0; li0 < n; li0 += 256) {
        int li = li0 + t;
        unsigned int low = 0;
        int bl = -1, bt = -1;
        if (li < n) {
            low = slow[li];
            bl = (int)(low & 0x1FFFF) / RL;
            bt = (int)(low >> 17) / RT;
        }
#pragma unroll
        for (int b = 0; b < 8; ++b) {
            unsigned long long m = __ballot(bl == b);
            if (m) {
                int leader = __ffsll((unsigned long long)m) - 1;
                int rank = __popcll(m & ((1ULL << lane) - 1ULL));
                int wbase = 0;
                if (lane == leader) wbase = atomicAdd(&h[b], __popcll(m));
                wbase = __shfl(wbase, leader);
                if (bl == b) {
                    int i = min(base_s[b] + wbase + rank, CAP - 1);
                    bkt_l[(size_t)b * CAP + i] =
                        ((unsigned long long)(unsigned int)(beg + li) << 32) | low;
                }
            }
            m = __ballot(bt == b);
            if (m) {
                int leader = __ffsll((unsigned long long)m) - 1;
                int rank = __popcll(m & ((1ULL << lane) - 1ULL));
                int wbase = 0;
                if (lane == leader) wbase = atomicAdd(&h[8 + b], __popcll(m));
                wbase = __shfl(wbase, leader);
                if (bt == b) {
                    int i = min(base_s[8 + b] + wbase + rank, CAP - 1);
                    bkt_t[(size_t)b * CAP + i] = low;
                }
            }
        }
    }
}

// ---------------- phase 2a: per-slice LDS histogram, NO global atomics ----------------
__launch_bounds__(256)
__global__ void count_slices(const unsigned long long* __restrict__ bkt_l,
                             const unsigned int* __restrict__ bkt_t,
                             const int* __restrict__ gcur,
                             int* __restrict__ cnts_l, int* __restrict__ cnts_t) {
    __shared__ int h[RL];  // 50 KB
    int bi = blockIdx.x;
    int t = threadIdx.x;
    if (bi < NSLB) {
        int p = bi & 7, slice = bi >> 3;
        for (int j = t; j < RL; j += 256) h[j] = 0;
        __syncthreads();
        int n = min(gcur[p], CAP);
        int ss = (n + NSLICE - 1) / NSLICE;
        int beg = slice * ss, end = min(beg + ss, n);
        const unsigned long long* b = bkt_l + (size_t)p * CAP;
        for (int i = beg + t; i < end; i += 256)
            atomicAdd(&h[((unsigned int)b[i] & 0x1FFFF) - p * RL], 1);
        __syncthreads();
        int* dst = cnts_l + (size_t)slice * N_LIG + p * RL;
        for (int j = t; j < RL; j += 256) dst[j] = h[j];
    } else {
        int k = bi - NSLB;
        int p = k & 7, slice = k >> 3;
        for (int j = t; j < RT; j += 256) h[j] = 0;
        __syncthreads();
        int n = min(gcur[8 + p], CAP);
        int ss = (n + NSLICE - 1) / NSLICE;
        int beg = slice * ss, end = min(beg + ss, n);
        const unsigned int* b = bkt_t + (size_t)p * CAP;
        for (int i = beg + t; i < end; i += 256)
            atomicAdd(&h[(int)(b[i] >> 17) - p * RT], 1);
        __syncthreads();
        int* dst = cnts_t + (size_t)slice * N_TGT + p * RT;
        for (int j = t; j < RT; j += 256) dst[j] = h[j];
    }
}

// ---------------- merged scan: node totals + in-place cross-slice exclusive prefix ----------------
__global__ void scan_block2(int* __restrict__ cnts_l, int* __restrict__ out_l,
                            int* __restrict__ bs_l, int nL, int nbL,
                            int* __restrict__ cnts_t, int* __restrict__ out_t,
                            int* __restrict__ bs_t, int nT) {
    __shared__ int ts[256];
    int* cnts; int* out; int* bsum; int n; int bi; size_t N;
    if ((int)blockIdx.x < nbL) { cnts = cnts_l; out = out_l; bsum = bs_l; n = nL; bi = blockIdx.x; N = N_LIG; }
    else { cnts = cnts_t; out = out_t; bsum = bs_t; n = nT; bi = blockIdx.x - nbL; N = N_TGT; }
    int t = threadIdx.x;
    int base = bi * 1024 + t * 4;
    int v[4] = {0, 0, 0, 0};
    for (int sl = 0; sl < NSLICE; ++sl) {
        size_t o = (size_t)sl * N + base;
#pragma unroll
        for (int i = 0; i < 4; i++) {
            if (base + i < n) {
                int c = cnts[o + i];
                cnts[o + i] = v[i];
                v[i] += c;
            }
        }
    }
    int s = v[0] + v[1] + v[2] + v[3];
    ts[t] = s;
    __syncthreads();
    for (int ofs = 1; ofs < 256; ofs <<= 1) {
        int x = (t >= ofs) ? ts[t - ofs] : 0;
        __syncthreads();
        ts[t] += x;
        __syncthreads();
    }
    int run = (t == 0) ? 0 : ts[t - 1];
    if (t == 255) bsum[bi] = ts[255];
#pragma unroll
    for (int i = 0; i < 4; i++) {
        if (base + i < n) out[base + i] = run;
        run += v[i];
    }
}

__global__ void scan_top2(int* __restrict__ bs_l, int nbL, int* __restrict__ bs_t, int nbT) {
    __shared__ int ts[256];
    int* bsum = (blockIdx.x == 0) ? bs_l : bs_t;
    int nb = (blockIdx.x == 0) ? nbL : nbT;
    int t = threadIdx.x;
    ts[t] = (t < nb) ? bsum[t] : 0;
    __syncthreads();
    for (int ofs = 1; ofs < 256; ofs <<= 1) {
        int x = (t >= ofs) ? ts[t - ofs] : 0;
        __syncthreads();
        ts[t] += x;
        __syncthreads();
    }
    int excl = (t == 0) ? 0 : ts[t - 1];
    if (t < nb) bsum[t] = excl;
}

__global__ void add_off2(int* __restrict__ rp_l, const int* __restrict__ bs_l,
                         int* __restrict__ rp_t, const int* __restrict__ bs_t) {
    int i = blockIdx.x * blockDim.x + threadIdx.x;
    if (i < N_LIG) {
        rp_l[i] += bs_l[i >> 10];
        if (i == 0) rp_l[N_LIG] = NEDGE;
    } else if (i < N_LIG + N_TGT) {
        int j = i - N_LIG;
        rp_t[j] += bs_t[j >> 10];
        if (j == 0) rp_t[N_TGT] = NEDGE;
    }
}

// ---------------- phase 2b: fill CSR via LDS cursors (no global atomics) ----------------
// elist_l entry: int2(low, e) where low = (d<<17)|s
__launch_bounds__(256)
__global__ void fill_slices(const unsigned long long* __restrict__ bkt_l,
                            const unsigned int* __restrict__ bkt_t,
                            const int* __restrict__ gcur,
                            const int* __restrict__ rowptr_l, const int* __restrict__ rowptr_t,
                            const int* __restrict__ cnts_l, const int* __restrict__ cnts_t,
                            int2* __restrict__ elist_l, int* __restrict__ nbr_t) {
    __shared__ int cur[RL];  // 50 KB
    int bi = blockIdx.x;
    int t = threadIdx.x;
    if (bi < NSLB) {
        int p = bi & 7, slice = bi >> 3;
        const int* rp = rowptr_l + p * RL;
        const int* pf = cnts_l + (size_t)slice * N_LIG + p * RL;
        for (int j = t; j < RL; j += 256) cur[j] = rp[j] + pf[j];
        __syncthreads();
        int n = min(gcur[p], CAP);
        int ss = (n + NSLICE - 1) / NSLICE;
        int beg = slice * ss, end = min(beg + ss, n);
        const unsigned long long* b = bkt_l + (size_t)p * CAP;
        for (int i = beg + t; i < end; i += 256) {
            unsigned long long v = b[i];
            unsigned int low = (unsigned int)v;
            int pos = atomicAdd(&cur[(low & 0x1FFFF) - p * RL], 1);
            elist_l[pos] = make_int2((int)low, (int)(v >> 32));
        }
    } else {
        int k = bi - NSLB;
        int p = k & 7, slice = k >> 3;
        const int* rp = rowptr_t + p * RT;
        const int* pf = cnts_t + (size_t)slice * N_TGT + p * RT;
        for (int j = t; j < RT; j += 256) cur[j] = rp[j] + pf[j];
        __syncthreads();
        int n = min(gcur[8 + p], CAP);
        int ss = (n + NSLICE - 1) / NSLICE;
        int beg = slice * ss, end = min(beg + ss, n);
        const unsigned int* b = bkt_t + (size_t)p * CAP;
        for (int i = beg + t; i < end; i += 256) {
            unsigned int v = b[i];
            int pos = atomicAdd(&cur[(v >> 17) - p * RT], 1);
            nbr_t[pos] = v & 0x1FFFF;
        }
    }
}

// ---------------- gather-mean: 16-lane group per node, unroll-8, no shuffles ----------------
__launch_bounds__(256)
__global__ void gather_g(const unsigned short* __restrict__ feat,
                         const int* __restrict__ rowptr, const int* __restrict__ nbr,
                         int stride, int shr, const float* __restrict__ bias,
                         unsigned short* __restrict__ out, int N) {
    int node = (blockIdx.x * blockDim.x + threadIdx.x) >> 4;
    if (node >= N) return;
    int l16 = threadIdx.x & 15;
    int beg = rowptr[node], end = rowptr[node + 1];
    const uint4v* f4 = (const uint4v*)feat;
    float acc[8] = {0.f, 0.f, 0.f, 0.f, 0.f, 0.f, 0.f, 0.f};
    int j = beg;
    for (; j + 8 <= end; j += 8) {
        uint4v v[8];
#pragma unroll
        for (int q = 0; q < 8; ++q)
            v[q] = f4[(size_t)(((unsigned int)nbr[(j + q) * stride]) >> shr) * 16 + l16];
#pragma unroll
        for (int q = 0; q < 8; ++q) {
#pragma unroll
            for (int w = 0; w < 4; ++w) {
                acc[2 * w] += bs2f(v[q][w] & 0xffff);
                acc[2 * w + 1] += bs2f(v[q][w] >> 16);
            }
        }
    }
    for (; j + 4 <= end; j += 4) {
        uint4v v[4];
#pragma unroll
        for (int q = 0; q < 4; ++q)
            v[q] = f4[(size_t)(((unsigned int)nbr[(j + q) * stride]) >> shr) * 16 + l16];
#pragma unroll
        for (int q = 0; q < 4; ++q) {
#pragma unroll
            for (int w = 0; w < 4; ++w) {
                acc[2 * w] += bs2f(v[q][w] & 0xffff);
                acc[2 * w + 1] += bs2f(v[q][w] >> 16);
            }
        }
    }
    for (; j < end; ++j) {
        unsigned int n0 = ((unsigned int)nbr[j * stride]) >> shr;
        uint4v v0 = f4[(size_t)n0 * 16 + l16];
#pragma unroll
        for (int q = 0; q < 4; ++q) {
            acc[2 * q] += bs2f(v0[q] & 0xffff);
            acc[2 * q + 1] += bs2f(v0[q] >> 16);
        }
    }
    float inv = 1.f / (float)max(end - beg, 1);
    uint4v o;
#pragma unroll
    for (int q = 0; q < 4; ++q) {
        float m0 = acc[2 * q] * inv, m1 = acc[2 * q + 1] * inv;
        if (bias) {
            m0 = fmaxf(m0 + bias[l16 * 8 + 2 * q], 0.f);
            m1 = fmaxf(m1 + bias[l16 * 8 + 2 * q + 1], 0.f);
        }
        o[q] = (unsigned int)f2bs(m0) | ((unsigned int)f2bs(m1) << 16);
    }
    ((uint4v*)out)[(size_t)node * 16 + l16] = o;
}

// ---------------- edge MLP, flat edge-parallel over CSR-ordered elist ----------------
__launch_bounds__(256)
__global__ void edge_mlp_flat(const unsigned short* __restrict__ A16, const unsigned short* __restrict__ B16,
                              const int2* __restrict__ elist,
                              const float* __restrict__ Wp2, const float* __restrict__ bp2,
                              float* __restrict__ out, int E, int ngroups) {
    int gid = (blockIdx.x * blockDim.x + threadIdx.x) >> 4;
    if (gid >= ngroups) return;
    int l16 = threadIdx.x & 15;
    int chunk = (E + ngroups - 1) / ngroups;
    int beg = gid * chunk;
    int end = min(beg + chunk, E);
    if (beg >= end) return;
    float4 w0 = *(const float4*)&Wp2[l16 * 8];
    float4 w1 = *(const float4*)&Wp2[l16 * 8 + 4];
    float wv[8] = {w0.x, w0.y, w0.z, w0.w, w1.x, w1.y, w1.z, w1.w};
    float bp = bp2[0];
    int prev_s = -1;
    float a[8];
    for (int p = beg; p < end; ++p) {
        long long de2 = *(const long long*)&elist[p];
        unsigned int low = (unsigned int)de2;
        int e = (int)(de2 >> 32);
        int s = (int)(low & 0x1FFFF);
        unsigned int d = low >> 17;
        if (s != prev_s) {
            uint4v ua = *(const uint4v*)&A16[(size_t)s * H + l16 * 8];
#pragma unroll
            for (int q = 0; q < 4; ++q) {
                a[2 * q] = bs2f(ua[q] & 0xffff);
                a[2 * q + 1] = bs2f(ua[q] >> 16);
            }
            prev_s = s;
        }
        uint4v ub = *(const uint4v*)&B16[(size_t)d * H + l16 * 8];
        float acc = 0.f;
#pragma unroll
        for (int q = 0; q < 4; ++q) {
            acc += fmaxf(a[2 * q] + bs2f(ub[q] & 0xffff), 0.f) * wv[2 * q];
            acc += fmaxf(a[2 * q + 1] + bs2f(ub[q] >> 16), 0.f) * wv[2 * q + 1];
        }
        acc += __shfl_xor(acc, 8);
        acc += __shfl_xor(acc, 4);
        acc += __shfl_xor(acc, 2);
        acc += __shfl_xor(acc, 1);
        if (l16 == 0) __builtin_nontemporal_store(acc + bp, &out[e]);
    }
}

extern "C" void kernel_launch(void* const* d_in, const int* in_sizes, int n_in,
                              void* d_out, int out_size, void* d_ws, size_t ws_size,
                              hipStream_t stream) {
    const float* x_lig = (const float*)d_in[0];
    const float* x_tgt = (const float*)d_in[1];
    const int* es = (const int*)d_in[2];
    const int* ed = (const int*)d_in[3];
    const float* W_lig = (const float*)d_in[4];
    const float* b_lig = (const float*)d_in[5];
    const float* W_tgt = (const float*)d_in[6];
    const float* b_tgt = (const float*)d_in[7];
    const float* W1f = (const float*)d_in[8];
    const float* b1f = (const float*)d_in[9];
    const float* W1r = (const float*)d_in[10];
    const float* b1r = (const float*)d_in[11];
    const float* W2f = (const float*)d_in[12];
    const float* b2f = (const float*)d_in[13];
    const float* W2r = (const float*)d_in[14];
    const float* b2r = (const float*)d_in[15];
    const float* Wp1 = (const float*)d_in[16];
    const float* bp1 = (const float*)d_in[17];
    const float* Wp2 = (const float*)d_in[18];
    const float* bp2 = (const float*)d_in[19];
    float* out = (float*)d_out;

    char* base = (char*)d_ws;
    size_t off = 0;
    auto alloc = [&](size_t bytes) { char* p = base + off; off = (off + bytes + 255) & ~(size_t)255; return p; };
    unsigned short* L0 = (unsigned short*)alloc((size_t)N_LIG * H * 2);  // h_lig layer0 out / A16
    unsigned short* L1 = (unsigned short*)alloc((size_t)N_LIG * H * 2);  // h_lig layer1 in
    unsigned short* T0 = (unsigned short*)alloc((size_t)N_TGT * H * 2);
    unsigned short* T1 = (unsigned short*)alloc((size_t)N_TGT * H * 2);  // agg_t / B16
    unsigned short* G  = (unsigned short*)alloc((size_t)N_TGT * H * 2);  // T0 @ Wr pre-transform
    unsigned short* Pe0 = (unsigned short*)alloc((size_t)N_TGT * H * 2); // embed K-split partials
    unsigned short* Pe1 = (unsigned short*)alloc((size_t)N_TGT * H * 2);
    unsigned short* Wt_tgt = (unsigned short*)alloc((size_t)128 * 1280 * 2);
    unsigned short* Wt1f = (unsigned short*)alloc(128 * 128 * 2);
    unsigned short* Wt1r = (unsigned short*)alloc(128 * 128 * 2);
    unsigned short* Wt2f = (unsigned short*)alloc(128 * 128 * 2);
    unsigned short* Wt2r = (unsigned short*)alloc(128 * 128 * 2);
    unsigned short* WtA = (unsigned short*)alloc(128 * 128 * 2);
    unsigned short* WtB = (unsigned short*)alloc(128 * 128 * 2);
    int* cnts_l = (int*)alloc((size_t)NSLICE * N_LIG * 4);
    int* cnts_t = (int*)alloc((size_t)NSLICE * N_TGT * 4);
    int* rowptr_l = (int*)alloc((N_LIG + 4) * 4);
    int* rowptr_t = (int*)alloc((N_TGT + 4) * 4);
    int* bsum_l = (int*)alloc(256 * 4);
    int* bsum_t = (int*)alloc(256 * 4);
    int* gcur = (int*)alloc(16 * 4);
    int2* elist_l = (int2*)alloc((size_t)NEDGE * 8);
    int* nbr_t = (int*)alloc((size_t)NEDGE * 4);
    unsigned long long* bkt_l = (unsigned long long*)alloc((size_t)NXCD * CAP * 8);
    unsigned int* bkt_t = (unsigned int*)alloc((size_t)NXCD * CAP * 4);

    const int ligBlocks128 = (N_LIG + 127) / 128;   // 782
    const int tgtBlocks128 = (N_TGT + 127) / 128;   // 157
    const int nbL = (N_LIG + 1023) / 1024;
    const int nbT = (N_TGT + 1023) / 1024;

    // 0. weight prep (transpose + bf16)
    transpose_w<<<(1280 * 128 + 255) / 256, 256, 0, stream>>>(W_tgt, Wt_tgt, 1280);
    P6 p6;
    p6.w[0] = W1f; p6.o[0] = Wt1f;
    p6.w[1] = W1r; p6.o[1] = Wt1r;
    p6.w[2] = W2f; p6.o[2] = Wt2f;
    p6.w[3] = W2r; p6.o[3] = Wt2r;
    p6.w[4] = Wp1;           p6.o[4] = WtA;
    p6.w[5] = Wp1 + 128 * H; p6.o[5] = WtB;
    transpose6<<<6 * 64, 256, 0, stream>>>(p6);

    // 1. node embeddings; x_tgt GEMM K-split-2 in one launch (314 blocks) + reduce
    lin4_bf16<<<(N_LIG * 16 + 255) / 256, 256, 0, stream>>>(x_lig, W_lig, b_lig, L0, N_LIG);
    gemm_embed_split<<<tgtBlocks128 * 2, 512, 0, stream>>>(x_tgt, Wt_tgt, Pe0, Pe1, N_TGT);
    reduce_embed<<<(N_TGT * 64 + 255) / 256, 256, 0, stream>>>(
        (const unsigned int*)Pe0, (const unsigned int*)Pe1, b_tgt, (unsigned int*)T0, N_TGT * 64);

    // 2. CSR build
    zero_gcur<<<1, 64, 0, stream>>>(gcur);
    bin_edges<<<BBLK, 256, 0, stream>>>(es, ed, bkt_l, bkt_t, gcur, NEDGE);
    count_slices<<<2 * NSLB, 256, 0, stream>>>(bkt_l, bkt_t, gcur, cnts_l, cnts_t);
    scan_block2<<<nbL + nbT, 256, 0, stream>>>(cnts_l, rowptr_l, bsum_l, N_LIG, nbL,
                                               cnts_t, rowptr_t, bsum_t, N_TGT);
    scan_top2<<<2, 256, 0, stream>>>(bsum_l, nbL, bsum_t, nbT);
    add_off2<<<(N_LIG + N_TGT + 255) / 256, 256, 0, stream>>>(rowptr_l, bsum_l, rowptr_t, bsum_t);
    fill_slices<<<2 * NSLB, 256, 0, stream>>>(bkt_l, bkt_t, gcur, rowptr_l, rowptr_t,
                                              cnts_l, cnts_t, elist_l, nbr_t);

    // 3a. layer 0: G = T0 @ W1r; T-gather(L0); L-gather(G -> L1); T-GEMM
    gemm_bf16<<<tgtBlocks128, 512, 0, stream>>>(T0, Wt1r, nullptr, G, N_TGT, 0);
    gather_g<<<(int)(((size_t)N_TGT * 16 + 255) / 256), 256, 0, stream>>>(
        L0, rowptr_t, nbr_t, 1, 0, nullptr, T1, N_TGT);
    gather_g<<<(int)(((size_t)N_LIG * 16 + 255) / 256), 256, 0, stream>>>(
        G, rowptr_l, (const int*)elist_l, 2, 17, b1r, L1, N_LIG);
    gemm_bf16<<<tgtBlocks128, 512, 0, stream>>>(T1, Wt1f, b1f, T0, N_TGT, 1);

    // 3b. layer 1: G = T0 @ W2r; T-gather(L1); T-GEMM
    gemm_bf16<<<tgtBlocks128, 512, 0, stream>>>(T0, Wt2r, nullptr, G, N_TGT, 0);
    gather_g<<<(int)(((size_t)N_TGT * 16 + 255) / 256), 256, 0, stream>>>(
        L1, rowptr_t, nbr_t, 1, 0, nullptr, T1, N_TGT);
    gemm_bf16<<<tgtBlocks128, 512, 0, stream>>>(T1, Wt2f, b2f, T0, N_TGT, 1);

    // 4. fused: A16 = relu(mean(G[d])+b2r) @ WtA  (final h_lig never materialized)
    gather_gemm_A<<<ligBlocks128, 512, 0, stream>>>(G, rowptr_l, (const int*)elist_l, b2r, WtA, L0, N_LIG);
    //    B16 = h_tgt @ WtB + bp1
    gemm_bf16<<<tgtBlocks128, 512, 0, stream>>>(T0, WtB, bp1, T1, N_TGT, 0);

    // 5. per-edge, flat edge-parallel in CSR order: pred = relu(A[s]+B[d]) . Wp2 + bp2
    const int ngroups = 32768;
    edge_mlp_flat<<<ngroups / 16, 256, 0, stream>>>(
        L0, T1, elist_l, Wp2, bp2, out, NEDGE, ngroups);
}

// Round 21
// 369.239 us; speedup vs baseline: 1.0355x; 1.0355x over previous
//
#include <hip/hip_runtime.h>
#include <hip/hip_bf16.h>

#define N_LIG 100000
#define N_TGT 20000
#define NEDGE 1000000
#define H 128
#define NXCD 8
#define RL 12500   // ligand ids per partition (8*12500 = 100000)
#define RT 2500    // target ids per partition (8*2500 = 20000)
#define CAP 131072 // per-bucket capacity (mean 125000, sigma ~331)
#define NSLICE 16  // sub-slices per bucket for count/fill
#define NSLB (NSLICE * NXCD)  // 128 blocks per side

typedef __attribute__((ext_vector_type(8))) short short8v;
typedef __attribute__((ext_vector_type(4))) float f32x4;
typedef __attribute__((ext_vector_type(4))) unsigned int uint4v;

// ---- bf16 helpers (manual RTN-even, bit ops only) ----
__device__ __forceinline__ unsigned short f2bs(float f) {
    unsigned int u = __float_as_uint(f);
    u += 0x7fff + ((u >> 16) & 1);
    return (unsigned short)(u >> 16);
}
__device__ __forceinline__ float bs2f(unsigned int s) {
    return __uint_as_float(s << 16);
}

// ---------------- weight transpose+convert: W[K][128] f32 -> Wt[128][K] bf16 ----------------
__global__ void transpose_w(const float* __restrict__ W, unsigned short* __restrict__ Wt, int K) {
    int idx = blockIdx.x * blockDim.x + threadIdx.x;
    if (idx >= K * 128) return;
    int k = idx >> 7, c = idx & 127;
    Wt[(size_t)c * K + k] = f2bs(W[idx]);
}

// six 128x128 transposes in one launch
struct P6 { const float* w[6]; unsigned short* o[6]; };
__global__ void transpose6(P6 p) {
    int idx = blockIdx.x * blockDim.x + threadIdx.x;  // 6*16384
    int which = idx >> 14;
    int rem = idx & 16383;
    int k = rem >> 7, c = rem & 127;
    p.o[which][(size_t)c * 128 + k] = f2bs(p.w[which][rem]);
}

// ---------------- ligand embed: K=4, bf16 out ----------------
__global__ void lin4_bf16(const float* __restrict__ X, const float* __restrict__ W,
                          const float* __restrict__ b, unsigned short* __restrict__ Y, int N) {
    int idx = blockIdx.x * blockDim.x + threadIdx.x;  // N*16, 8 cols each
    if (idx >= N * 16) return;
    int r = idx >> 4;
    int c = (idx & 15) * 8;
    float x0 = X[r * 4 + 0], x1 = X[r * 4 + 1], x2 = X[r * 4 + 2], x3 = X[r * 4 + 3];
    unsigned int o[4];
#pragma unroll
    for (int p = 0; p < 4; ++p) {
        float v0 = b[c + 2 * p] + x0 * W[c + 2 * p] + x1 * W[H + c + 2 * p] +
                   x2 * W[2 * H + c + 2 * p] + x3 * W[3 * H + c + 2 * p];
        float v1 = b[c + 2 * p + 1] + x0 * W[c + 2 * p + 1] + x1 * W[H + c + 2 * p + 1] +
                   x2 * W[2 * H + c + 2 * p + 1] + x3 * W[3 * H + c + 2 * p + 1];
        o[p] = (unsigned int)f2bs(v0) | ((unsigned int)f2bs(v1) << 16);
    }
    uint4 u = make_uint4(o[0], o[1], o[2], o[3]);
    *(uint4*)&Y[(size_t)r * H + c] = u;
}

// ---------------- MFMA GEMM: Y_bf16[N][128] = act(X_bf16[N][128] @ W + bias) ----------
__launch_bounds__(512)
__global__ void gemm_bf16(const unsigned short* __restrict__ X,
                          const unsigned short* __restrict__ Wt,
                          const float* __restrict__ bias,
                          unsigned short* __restrict__ Y,
                          int N, int do_relu) {
    __shared__ unsigned short Ws[128 * 128];  // 32 KB, swizzled; reused by epilogue
    const int t = threadIdx.x;
    const int wv = t >> 6;
    const int lane = t & 63;
    const int lr = lane & 15;
    const int kb = lane >> 4;
    const int row0 = blockIdx.x * 128;
    const int wrow = wv * 16;

    f32x4 acc[8];
#pragma unroll
    for (int i = 0; i < 8; ++i) acc[i] = (f32x4){0.f, 0.f, 0.f, 0.f};

    int arow = row0 + wrow + lr;
    if (arow >= N) arow = N - 1;
    const unsigned short* xrow = X + (size_t)arow * 128;

#pragma unroll
    for (int i = 0; i < 4; ++i) {
        int li = t + i * 512;
        int r = li >> 4;
        int cb = (li & 15) << 4;
        int4 v = *(const int4*)(Wt + (size_t)r * 128 + (cb >> 1));
        *(int4*)((char*)Ws + r * 256 + (cb ^ ((r & 7) << 4))) = v;
    }
    short8v a[4];
#pragma unroll
    for (int ks = 0; ks < 4; ++ks)
        a[ks] = *(const short8v*)(xrow + ks * 32 + kb * 8);
    __syncthreads();
#pragma unroll
    for (int ks = 0; ks < 4; ++ks) {
        int ofs = ks * 64 + kb * 16;
#pragma unroll
        for (int ct = 0; ct < 8; ++ct) {
            int c = ct * 16 + lr;
            short8v b = *(const short8v*)((const char*)Ws + c * 256 + (ofs ^ ((c & 7) << 4)));
            acc[ct] = __builtin_amdgcn_mfma_f32_16x16x32_bf16(a[ks], b, acc[ct], 0, 0, 0);
        }
    }
    __syncthreads();
#pragma unroll
    for (int ct = 0; ct < 8; ++ct) {
        int col = ct * 16 + lr;
        float bv = bias ? bias[col] : 0.f;
#pragma unroll
        for (int r = 0; r < 4; ++r) {
            float v = acc[ct][r] + bv;
            if (do_relu) v = fmaxf(v, 0.f);
            Ws[(wrow + kb * 4 + r) * 128 + col] = f2bs(v);
        }
    }
    __syncthreads();
#pragma unroll
    for (int i = 0; i < 4; ++i) {
        int li = t + i * 512;
        int r = li >> 4;
        int c8 = (li & 15) << 3;
        int grow = row0 + r;
        if (grow < N)
            *(uint4*)&Y[(size_t)grow * H + c8] = *(const uint4*)&Ws[r * 128 + c8];
    }
}

// ---------------- embed GEMM, K=1280 split-2 in one launch ----------------
__launch_bounds__(512)
__global__ void gemm_embed_split(const float* __restrict__ Xf32,
                                 const unsigned short* __restrict__ Wt,
                                 unsigned short* __restrict__ P0,
                                 unsigned short* __restrict__ P1, int N) {
    __shared__ unsigned short Ws[128 * 128];
    const int t = threadIdx.x;
    const int rb = blockIdx.x >> 1;
    const int sp = blockIdx.x & 1;
    const int K = 1280;
    const int kc0 = sp * 5, kcEnd = kc0 + 5;
    unsigned short* Y = sp ? P1 : P0;
    const int wv = t >> 6;
    const int lane = t & 63;
    const int lr = lane & 15;
    const int kb = lane >> 4;
    const int row0 = rb * 128;
    const int wrow = wv * 16;

    f32x4 acc[8];
#pragma unroll
    for (int i = 0; i < 8; ++i) acc[i] = (f32x4){0.f, 0.f, 0.f, 0.f};

    int arow = row0 + wrow + lr;
    if (arow >= N) arow = N - 1;
    const float* xrowf = Xf32 + (size_t)arow * K;

    for (int kc = kc0; kc < kcEnd; ++kc) {
        if (kc != kc0) __syncthreads();
#pragma unroll
        for (int i = 0; i < 4; ++i) {
            int li = t + i * 512;
            int r = li >> 4;
            int cb = (li & 15) << 4;
            int4 v = *(const int4*)(Wt + (size_t)r * K + (kc << 7) + (cb >> 1));
            *(int4*)((char*)Ws + r * 256 + (cb ^ ((r & 7) << 4))) = v;
        }
        short8v a[4];
#pragma unroll
        for (int ks = 0; ks < 4; ++ks) {
            const float* p = xrowf + (kc << 7) + ks * 32 + kb * 8;
            float4 f0 = *(const float4*)p;
            float4 f1 = *(const float4*)(p + 4);
            short8v av;
            av[0] = (short)f2bs(f0.x); av[1] = (short)f2bs(f0.y);
            av[2] = (short)f2bs(f0.z); av[3] = (short)f2bs(f0.w);
            av[4] = (short)f2bs(f1.x); av[5] = (short)f2bs(f1.y);
            av[6] = (short)f2bs(f1.z); av[7] = (short)f2bs(f1.w);
            a[ks] = av;
        }
        __syncthreads();
#pragma unroll
        for (int ks = 0; ks < 4; ++ks) {
            int ofs = ks * 64 + kb * 16;
#pragma unroll
            for (int ct = 0; ct < 8; ++ct) {
                int c = ct * 16 + lr;
                short8v b = *(const short8v*)((const char*)Ws + c * 256 + (ofs ^ ((c & 7) << 4)));
                acc[ct] = __builtin_amdgcn_mfma_f32_16x16x32_bf16(a[ks], b, acc[ct], 0, 0, 0);
            }
        }
    }
    __syncthreads();
#pragma unroll
    for (int ct = 0; ct < 8; ++ct) {
        int col = ct * 16 + lr;
#pragma unroll
        for (int r = 0; r < 4; ++r)
            Ws[(wrow + kb * 4 + r) * 128 + col] = f2bs(acc[ct][r]);
    }
    __syncthreads();
#pragma unroll
    for (int i = 0; i < 4; ++i) {
        int li = t + i * 512;
        int r = li >> 4;
        int c8 = (li & 15) << 3;
        int grow = row0 + r;
        if (grow < N)
            *(uint4*)&Y[(size_t)grow * H + c8] = *(const uint4*)&Ws[r * 128 + c8];
    }
}

// T0 = bf16(P0 + P1 + bias)
__global__ void reduce_embed(const unsigned int* __restrict__ P0, const unsigned int* __restrict__ P1,
                             const float* __restrict__ bias, unsigned int* __restrict__ T0, int n) {
    int i = blockIdx.x * blockDim.x + threadIdx.x;
    if (i >= n) return;
    int c2 = i & 63;
    unsigned int a = P0[i], b = P1[i];
    float f0 = bs2f(a & 0xffff) + bs2f(b & 0xffff) + bias[2 * c2];
    float f1 = bs2f(a >> 16) + bs2f(b >> 16) + bias[2 * c2 + 1];
    T0[i] = (unsigned int)f2bs(f0) | ((unsigned int)f2bs(f1) << 16);
}

// ---------------- CSR build phase 1: bin edges into 8 XCD buckets (two-pass, R18-proven) ----
__global__ void zero_gcur(int* __restrict__ g) {
    if (threadIdx.x < 16) g[threadIdx.x] = 0;
}

__launch_bounds__(256)
__global__ void bin_edges(const int* __restrict__ es, const int* __restrict__ ed,
                          unsigned long long* __restrict__ bkt_l, unsigned int* __restrict__ bkt_t,
                          int* __restrict__ gcur, int E) {
    __shared__ int h[16];
    __shared__ int base_s[16];
    int t = threadIdx.x;
    int lane = t & 63;
    if (t < 16) h[t] = 0;
    __syncthreads();
    int chunk = (E + gridDim.x - 1) / gridDim.x;
    int beg = blockIdx.x * chunk;
    int end = min(beg + chunk, E);
    for (int e0 = beg; e0 < end; e0 += 256) {
        int e = e0 + t;
        int bl = -1, bt = -1;
        if (e < end) { bl = es[e] / RL; bt = ed[e] / RT; }
#pragma unroll
        for (int b = 0; b < 8; ++b) {
            unsigned long long m = __ballot(bl == b);
            if (lane == 0 && m) atomicAdd(&h[b], __popcll(m));
            m = __ballot(bt == b);
            if (lane == 0 && m) atomicAdd(&h[8 + b], __popcll(m));
        }
    }
    __syncthreads();
    if (t < 16) {
        base_s[t] = atomicAdd(&gcur[t], h[t]);
        h[t] = 0;
    }
    __syncthreads();
    for (int e0 = beg; e0 < end; e0 += 256) {
        int e = e0 + t;
        int s = 0, d = 0, bl = -1, bt = -1;
        if (e < end) { s = es[e]; d = ed[e]; bl = s / RL; bt = d / RT; }
        unsigned int low = ((unsigned int)d << 17) | (unsigned int)s;
#pragma unroll
        for (int b = 0; b < 8; ++b) {
            unsigned long long m = __ballot(bl == b);
            if (m) {
                int leader = __ffsll((unsigned long long)m) - 1;
                int rank = __popcll(m & ((1ULL << lane) - 1ULL));
                int wbase = 0;
                if (lane == leader) wbase = atomicAdd(&h[b], __popcll(m));
                wbase = __shfl(wbase, leader);
                if (bl == b) {
                    int i = min(base_s[b] + wbase + rank, CAP - 1);
                    bkt_l[(size_t)b * CAP + i] = ((unsigned long long)(unsigned int)e << 32) | low;
                }
            }
            m = __ballot(bt == b);
            if (m) {
                int leader = __ffsll((unsigned long long)m) - 1;
                int rank = __popcll(m & ((1ULL << lane) - 1ULL));
                int wbase = 0;
                if (lane == leader) wbase = atomicAdd(&h[8 + b], __popcll(m));
                wbase = __shfl(wbase, leader);
                if (bt == b) {
                    int i = min(base_s[8 + b] + wbase + rank, CAP - 1);
                    bkt_t[(size_t)b * CAP + i] = low;
                }
            }
        }
    }
}

// ---------------- phase 2a: per-slice LDS histogram, NO global atomics ----------------
__launch_bounds__(256)
__global__ void count_slices(const unsigned long long* __restrict__ bkt_l,
                             const unsigned int* __restrict__ bkt_t,
                             const int* __restrict__ gcur,
                             int* __restrict__ cnts_l, int* __restrict__ cnts_t) {
    __shared__ int h[RL];  // 50 KB
    int bi = blockIdx.x;
    int t = threadIdx.x;
    if (bi < NSLB) {
        int p = bi & 7, slice = bi >> 3;
        for (int j = t; j < RL; j += 256) h[j] = 0;
        __syncthreads();
        int n = min(gcur[p], CAP);
        int ss = (n + NSLICE - 1) / NSLICE;
        int beg = slice * ss, end = min(beg + ss, n);
        const unsigned long long* b = bkt_l + (size_t)p * CAP;
        for (int i = beg + t; i < end; i += 256)
            atomicAdd(&h[((unsigned int)b[i] & 0x1FFFF) - p * RL], 1);
        __syncthreads();
        int* dst = cnts_l + (size_t)slice * N_LIG + p * RL;
        for (int j = t; j < RL; j += 256) dst[j] = h[j];
    } else {
        int k = bi - NSLB;
        int p = k & 7, slice = k >> 3;
        for (int j = t; j < RT; j += 256) h[j] = 0;
        __syncthreads();
        int n = min(gcur[8 + p], CAP);
        int ss = (n + NSLICE - 1) / NSLICE;
        int beg = slice * ss, end = min(beg + ss, n);
        const unsigned int* b = bkt_t + (size_t)p * CAP;
        for (int i = beg + t; i < end; i += 256)
            atomicAdd(&h[(int)(b[i] >> 17) - p * RT], 1);
        __syncthreads();
        int* dst = cnts_t + (size_t)slice * N_TGT + p * RT;
        for (int j = t; j < RT; j += 256) dst[j] = h[j];
    }
}

// ---------------- merged scan: node totals + in-place cross-slice exclusive prefix ----------------
__global__ void scan_block2(int* __restrict__ cnts_l, int* __restrict__ out_l,
                            int* __restrict__ bs_l, int nL, int nbL,
                            int* __restrict__ cnts_t, int* __restrict__ out_t,
                            int* __restrict__ bs_t, int nT) {
    __shared__ int ts[256];
    int* cnts; int* out; int* bsum; int n; int bi; size_t N;
    if ((int)blockIdx.x < nbL) { cnts = cnts_l; out = out_l; bsum = bs_l; n = nL; bi = blockIdx.x; N = N_LIG; }
    else { cnts = cnts_t; out = out_t; bsum = bs_t; n = nT; bi = blockIdx.x - nbL; N = N_TGT; }
    int t = threadIdx.x;
    int base = bi * 1024 + t * 4;
    int v[4] = {0, 0, 0, 0};
    for (int sl = 0; sl < NSLICE; ++sl) {
        size_t o = (size_t)sl * N + base;
#pragma unroll
        for (int i = 0; i < 4; i++) {
            if (base + i < n) {
                int c = cnts[o + i];
                cnts[o + i] = v[i];
                v[i] += c;
            }
        }
    }
    int s = v[0] + v[1] + v[2] + v[3];
    ts[t] = s;
    __syncthreads();
    for (int ofs = 1; ofs < 256; ofs <<= 1) {
        int x = (t >= ofs) ? ts[t - ofs] : 0;
        __syncthreads();
        ts[t] += x;
        __syncthreads();
    }
    int run = (t == 0) ? 0 : ts[t - 1];
    if (t == 255) bsum[bi] = ts[255];
#pragma unroll
    for (int i = 0; i < 4; i++) {
        if (base + i < n) out[base + i] = run;
        run += v[i];
    }
}

__global__ void scan_top2(int* __restrict__ bs_l, int nbL, int* __restrict__ bs_t, int nbT) {
    __shared__ int ts[256];
    int* bsum = (blockIdx.x == 0) ? bs_l : bs_t;
    int nb = (blockIdx.x == 0) ? nbL : nbT;
    int t = threadIdx.x;
    ts[t] = (t < nb) ? bsum[t] : 0;
    __syncthreads();
    for (int ofs = 1; ofs < 256; ofs <<= 1) {
        int x = (t >= ofs) ? ts[t - ofs] : 0;
        __syncthreads();
        ts[t] += x;
        __syncthreads();
    }
    int excl = (t == 0) ? 0 : ts[t - 1];
    if (t < nb) bsum[t] = excl;
}

__global__ void add_off2(int* __restrict__ rp_l, const int* __restrict__ bs_l,
                         int* __restrict__ rp_t, const int* __restrict__ bs_t) {
    int i = blockIdx.x * blockDim.x + threadIdx.x;
    if (i < N_LIG) {
        rp_l[i] += bs_l[i >> 10];
        if (i == 0) rp_l[N_LIG] = NEDGE;
    } else if (i < N_LIG + N_TGT) {
        int j = i - N_LIG;
        rp_t[j] += bs_t[j >> 10];
        if (j == 0) rp_t[N_TGT] = NEDGE;
    }
}

// ---------------- phase 2b: fill CSR via LDS cursors (no global atomics) ----------------
// elist_l entry: int2(low, e) where low = (d<<17)|s
__launch_bounds__(256)
__global__ void fill_slices(const unsigned long long* __restrict__ bkt_l,
                            const unsigned int* __restrict__ bkt_t,
                            const int* __restrict__ gcur,
                            const int* __restrict__ rowptr_l, const int* __restrict__ rowptr_t,
                            const int* __restrict__ cnts_l, const int* __restrict__ cnts_t,
                            int2* __restrict__ elist_l, int* __restrict__ nbr_t) {
    __shared__ int cur[RL];  // 50 KB
    int bi = blockIdx.x;
    int t = threadIdx.x;
    if (bi < NSLB) {
        int p = bi & 7, slice = bi >> 3;
        const int* rp = rowptr_l + p * RL;
        const int* pf = cnts_l + (size_t)slice * N_LIG + p * RL;
        for (int j = t; j < RL; j += 256) cur[j] = rp[j] + pf[j];
        __syncthreads();
        int n = min(gcur[p], CAP);
        int ss = (n + NSLICE - 1) / NSLICE;
        int beg = slice * ss, end = min(beg + ss, n);
        const unsigned long long* b = bkt_l + (size_t)p * CAP;
        for (int i = beg + t; i < end; i += 256) {
            unsigned long long v = b[i];
            unsigned int low = (unsigned int)v;
            int pos = atomicAdd(&cur[(low & 0x1FFFF) - p * RL], 1);
            elist_l[pos] = make_int2((int)low, (int)(v >> 32));
        }
    } else {
        int k = bi - NSLB;
        int p = k & 7, slice = k >> 3;
        const int* rp = rowptr_t + p * RT;
        const int* pf = cnts_t + (size_t)slice * N_TGT + p * RT;
        for (int j = t; j < RT; j += 256) cur[j] = rp[j] + pf[j];
        __syncthreads();
        int n = min(gcur[8 + p], CAP);
        int ss = (n + NSLICE - 1) / NSLICE;
        int beg = slice * ss, end = min(beg + ss, n);
        const unsigned int* b = bkt_t + (size_t)p * CAP;
        for (int i = beg + t; i < end; i += 256) {
            unsigned int v = b[i];
            int pos = atomicAdd(&cur[(v >> 17) - p * RT], 1);
            nbr_t[pos] = v & 0x1FFFF;
        }
    }
}

// ---------------- gather-mean: 16-lane group per node, unroll-4 (R14-proven) ----------------
__launch_bounds__(256)
__global__ void gather_g(const unsigned short* __restrict__ feat,
                         const int* __restrict__ rowptr, const int* __restrict__ nbr,
                         int stride, int shr, const float* __restrict__ bias,
                         unsigned short* __restrict__ out, int N) {
    int node = (blockIdx.x * blockDim.x + threadIdx.x) >> 4;
    if (node >= N) return;
    int l16 = threadIdx.x & 15;
    int beg = rowptr[node], end = rowptr[node + 1];
    const uint4v* f4 = (const uint4v*)feat;
    float acc[8] = {0.f, 0.f, 0.f, 0.f, 0.f, 0.f, 0.f, 0.f};
    int j = beg;
    for (; j + 4 <= end; j += 4) {
        unsigned int n0 = ((unsigned int)nbr[(j + 0) * stride]) >> shr;
        unsigned int n1 = ((unsigned int)nbr[(j + 1) * stride]) >> shr;
        unsigned int n2 = ((unsigned int)nbr[(j + 2) * stride]) >> shr;
        unsigned int n3 = ((unsigned int)nbr[(j + 3) * stride]) >> shr;
        uint4v v0 = f4[(size_t)n0 * 16 + l16];
        uint4v v1 = f4[(size_t)n1 * 16 + l16];
        uint4v v2 = f4[(size_t)n2 * 16 + l16];
        uint4v v3 = f4[(size_t)n3 * 16 + l16];
#pragma unroll
        for (int q = 0; q < 4; ++q) {
            acc[2 * q] += (bs2f(v0[q] & 0xffff) + bs2f(v1[q] & 0xffff)) +
                          (bs2f(v2[q] & 0xffff) + bs2f(v3[q] & 0xffff));
            acc[2 * q + 1] += (bs2f(v0[q] >> 16) + bs2f(v1[q] >> 16)) +
                              (bs2f(v2[q] >> 16) + bs2f(v3[q] >> 16));
        }
    }
    for (; j < end; ++j) {
        unsigned int n0 = ((unsigned int)nbr[j * stride]) >> shr;
        uint4v v0 = f4[(size_t)n0 * 16 + l16];
#pragma unroll
        for (int q = 0; q < 4; ++q) {
            acc[2 * q] += bs2f(v0[q] & 0xffff);
            acc[2 * q + 1] += bs2f(v0[q] >> 16);
        }
    }
    float inv = 1.f / (float)max(end - beg, 1);
    uint4v o;
#pragma unroll
    for (int q = 0; q < 4; ++q) {
        float m0 = acc[2 * q] * inv, m1 = acc[2 * q + 1] * inv;
        if (bias) {
            m0 = fmaxf(m0 + bias[l16 * 8 + 2 * q], 0.f);
            m1 = fmaxf(m1 + bias[l16 * 8 + 2 * q + 1], 0.f);
        }
        o[q] = (unsigned int)f2bs(m0) | ((unsigned int)f2bs(m1) << 16);
    }
    ((uint4v*)out)[(size_t)node * 16 + l16] = o;
}

// ---------------- edge MLP, flat edge-parallel over CSR-ordered elist ----------------
__launch_bounds__(256)
__global__ void edge_mlp_flat(const unsigned short* __restrict__ A16, const unsigned short* __restrict__ B16,
                              const int2* __restrict__ elist,
                              const float* __restrict__ Wp2, const float* __restrict__ bp2,
                              float* __restrict__ out, int E, int ngroups) {
    int gid = (blockIdx.x * blockDim.x + threadIdx.x) >> 4;
    if (gid >= ngroups) return;
    int l16 = threadIdx.x & 15;
    int chunk = (E + ngroups - 1) / ngroups;
    int beg = gid * chunk;
    int end = min(beg + chunk, E);
    if (beg >= end) return;
    float4 w0 = *(const float4*)&Wp2[l16 * 8];
    float4 w1 = *(const float4*)&Wp2[l16 * 8 + 4];
    float wv[8] = {w0.x, w0.y, w0.z, w0.w, w1.x, w1.y, w1.z, w1.w};
    float bp = bp2[0];
    int prev_s = -1;
    float a[8];
    for (int p = beg; p < end; ++p) {
        long long de2 = *(const long long*)&elist[p];
        unsigned int low = (unsigned int)de2;
        int e = (int)(de2 >> 32);
        int s = (int)(low & 0x1FFFF);
        unsigned int d = low >> 17;
        if (s != prev_s) {
            uint4v ua = *(const uint4v*)&A16[(size_t)s * H + l16 * 8];
#pragma unroll
            for (int q = 0; q < 4; ++q) {
                a[2 * q] = bs2f(ua[q] & 0xffff);
                a[2 * q + 1] = bs2f(ua[q] >> 16);
            }
            prev_s = s;
        }
        uint4v ub = *(const uint4v*)&B16[(size_t)d * H + l16 * 8];
        float acc = 0.f;
#pragma unroll
        for (int q = 0; q < 4; ++q) {
            acc += fmaxf(a[2 * q] + bs2f(ub[q] & 0xffff), 0.f) * wv[2 * q];
            acc += fmaxf(a[2 * q + 1] + bs2f(ub[q] >> 16), 0.f) * wv[2 * q + 1];
        }
        acc += __shfl_xor(acc, 8);
        acc += __shfl_xor(acc, 4);
        acc += __shfl_xor(acc, 2);
        acc += __shfl_xor(acc, 1);
        if (l16 == 0) __builtin_nontemporal_store(acc + bp, &out[e]);
    }
}

extern "C" void kernel_launch(void* const* d_in, const int* in_sizes, int n_in,
                              void* d_out, int out_size, void* d_ws, size_t ws_size,
                              hipStream_t stream) {
    const float* x_lig = (const float*)d_in[0];
    const float* x_tgt = (const float*)d_in[1];
    const int* es = (const int*)d_in[2];
    const int* ed = (const int*)d_in[3];
    const float* W_lig = (const float*)d_in[4];
    const float* b_lig = (const float*)d_in[5];
    const float* W_tgt = (const float*)d_in[6];
    const float* b_tgt = (const float*)d_in[7];
    const float* W1f = (const float*)d_in[8];
    const float* b1f = (const float*)d_in[9];
    const float* W1r = (const float*)d_in[10];
    const float* b1r = (const float*)d_in[11];
    const float* W2f = (const float*)d_in[12];
    const float* b2f = (const float*)d_in[13];
    const float* W2r = (const float*)d_in[14];
    const float* b2r = (const float*)d_in[15];
    const float* Wp1 = (const float*)d_in[16];
    const float* bp1 = (const float*)d_in[17];
    const float* Wp2 = (const float*)d_in[18];
    const float* bp2 = (const float*)d_in[19];
    float* out = (float*)d_out;

    char* base = (char*)d_ws;
    size_t off = 0;
    auto alloc = [&](size_t bytes) { char* p = base + off; off = (off + bytes + 255) & ~(size_t)255; return p; };
    unsigned short* L0 = (unsigned short*)alloc((size_t)N_LIG * H * 2);  // h_lig ping / final
    unsigned short* L1 = (unsigned short*)alloc((size_t)N_LIG * H * 2);  // h_lig pong / A16
    unsigned short* T0 = (unsigned short*)alloc((size_t)N_TGT * H * 2);
    unsigned short* T1 = (unsigned short*)alloc((size_t)N_TGT * H * 2);  // agg_t / B16
    unsigned short* G  = (unsigned short*)alloc((size_t)N_TGT * H * 2);  // T0 @ Wr pre-transform
    unsigned short* Pe0 = (unsigned short*)alloc((size_t)N_TGT * H * 2); // embed K-split partials
    unsigned short* Pe1 = (unsigned short*)alloc((size_t)N_TGT * H * 2);
    unsigned short* Wt_tgt = (unsigned short*)alloc((size_t)128 * 1280 * 2);
    unsigned short* Wt1f = (unsigned short*)alloc(128 * 128 * 2);
    unsigned short* Wt1r = (unsigned short*)alloc(128 * 128 * 2);
    unsigned short* Wt2f = (unsigned short*)alloc(128 * 128 * 2);
    unsigned short* Wt2r = (unsigned short*)alloc(128 * 128 * 2);
    unsigned short* WtA = (unsigned short*)alloc(128 * 128 * 2);
    unsigned short* WtB = (unsigned short*)alloc(128 * 128 * 2);
    int* cnts_l = (int*)alloc((size_t)NSLICE * N_LIG * 4);
    int* cnts_t = (int*)alloc((size_t)NSLICE * N_TGT * 4);
    int* rowptr_l = (int*)alloc((N_LIG + 4) * 4);
    int* rowptr_t = (int*)alloc((N_TGT + 4) * 4);
    int* bsum_l = (int*)alloc(256 * 4);
    int* bsum_t = (int*)alloc(256 * 4);
    int* gcur = (int*)alloc(16 * 4);
    int2* elist_l = (int2*)alloc((size_t)NEDGE * 8);
    int* nbr_t = (int*)alloc((size_t)NEDGE * 4);
    unsigned long long* bkt_l = (unsigned long long*)alloc((size_t)NXCD * CAP * 8);
    unsigned int* bkt_t = (unsigned int*)alloc((size_t)NXCD * CAP * 4);

    const int ligBlocks128 = (N_LIG + 127) / 128;   // 782
    const int tgtBlocks128 = (N_TGT + 127) / 128;   // 157
    const int nbL = (N_LIG + 1023) / 1024;
    const int nbT = (N_TGT + 1023) / 1024;

    // 0. weight prep (transpose + bf16)
    transpose_w<<<(1280 * 128 + 255) / 256, 256, 0, stream>>>(W_tgt, Wt_tgt, 1280);
    P6 p6;
    p6.w[0] = W1f; p6.o[0] = Wt1f;
    p6.w[1] = W1r; p6.o[1] = Wt1r;
    p6.w[2] = W2f; p6.o[2] = Wt2f;
    p6.w[3] = W2r; p6.o[3] = Wt2r;
    p6.w[4] = Wp1;           p6.o[4] = WtA;
    p6.w[5] = Wp1 + 128 * H; p6.o[5] = WtB;
    transpose6<<<6 * 64, 256, 0, stream>>>(p6);

    // 1. node embeddings; x_tgt GEMM K-split-2 in one launch (314 blocks) + reduce
    lin4_bf16<<<(N_LIG * 16 + 255) / 256, 256, 0, stream>>>(x_lig, W_lig, b_lig, L0, N_LIG);
    gemm_embed_split<<<tgtBlocks128 * 2, 512, 0, stream>>>(x_tgt, Wt_tgt, Pe0, Pe1, N_TGT);
    reduce_embed<<<(N_TGT * 64 + 255) / 256, 256, 0, stream>>>(
        (const unsigned int*)Pe0, (const unsigned int*)Pe1, b_tgt, (unsigned int*)T0, N_TGT * 64);

    // 2. CSR build
    zero_gcur<<<1, 64, 0, stream>>>(gcur);
    bin_edges<<<512, 256, 0, stream>>>(es, ed, bkt_l, bkt_t, gcur, NEDGE);
    count_slices<<<2 * NSLB, 256, 0, stream>>>(bkt_l, bkt_t, gcur, cnts_l, cnts_t);
    scan_block2<<<nbL + nbT, 256, 0, stream>>>(cnts_l, rowptr_l, bsum_l, N_LIG, nbL,
                                               cnts_t, rowptr_t, bsum_t, N_TGT);
    scan_top2<<<2, 256, 0, stream>>>(bsum_l, nbL, bsum_t, nbT);
    add_off2<<<(N_LIG + N_TGT + 255) / 256, 256, 0, stream>>>(rowptr_l, bsum_l, rowptr_t, bsum_t);
    fill_slices<<<2 * NSLB, 256, 0, stream>>>(bkt_l, bkt_t, gcur, rowptr_l, rowptr_t,
                                              cnts_l, cnts_t, elist_l, nbr_t);

    // 3a. layer 0: G = T0 @ W1r; T-gather(L0); L-gather(G -> L1); T-GEMM
    gemm_bf16<<<tgtBlocks128, 512, 0, stream>>>(T0, Wt1r, nullptr, G, N_TGT, 0);
    gather_g<<<(int)(((size_t)N_TGT * 16 + 255) / 256), 256, 0, stream>>>(
        L0, rowptr_t, nbr_t, 1, 0, nullptr, T1, N_TGT);
    gather_g<<<(int)(((size_t)N_LIG * 16 + 255) / 256), 256, 0, stream>>>(
        G, rowptr_l, (const int*)elist_l, 2, 17, b1r, L1, N_LIG);
    gemm_bf16<<<tgtBlocks128, 512, 0, stream>>>(T1, Wt1f, b1f, T0, N_TGT, 1);

    // 3b. layer 1: G = T0 @ W2r; T-gather(L1); T-GEMM; L-gather(G -> L0, final h_lig)
    gemm_bf16<<<tgtBlocks128, 512, 0, stream>>>(T0, Wt2r, nullptr, G, N_TGT, 0);
    gather_g<<<(int)(((size_t)N_TGT * 16 + 255) / 256), 256, 0, stream>>>(
        L1, rowptr_t, nbr_t, 1, 0, nullptr, T1, N_TGT);
    gemm_bf16<<<tgtBlocks128, 512, 0, stream>>>(T1, Wt2f, b2f, T0, N_TGT, 1);
    gather_g<<<(int)(((size_t)N_LIG * 16 + 255) / 256), 256, 0, stream>>>(
        G, rowptr_l, (const int*)elist_l, 2, 17, b2r, L0, N_LIG);

    // 4. edge-MLP factorization: A16 = h_lig @ WtA (unfused); B16 = h_tgt @ WtB + bp1
    gemm_bf16<<<ligBlocks128, 512, 0, stream>>>(L0, WtA, nullptr, L1, N_LIG, 0);
    gemm_bf16<<<tgtBlocks128, 512, 0, stream>>>(T0, WtB, bp1, T1, N_TGT, 0);

    // 5. per-edge, flat edge-parallel in CSR order: pred = relu(A[s]+B[d]) . Wp2 + bp2
    const int ngroups = 32768;
    edge_mlp_flat<<<ngroups / 16, 256, 0, stream>>>(
        L1, T1, elist_l, Wp2, bp2, out, NEDGE, ngroups);
}